// Round 3
// baseline (348.379 us; speedup 1.0000x reference)
//
#include <hip/hip_runtime.h>
#include <stdint.h>

#define GDIM   512
#define HID    150
#define HIDP   160    // HID padded to multiple of 16
#define NROWS  12000
#define KP1    31     // KMAX+1

typedef __attribute__((ext_vector_type(8))) short bf16x8;
typedef __attribute__((ext_vector_type(4))) float f32x4;
typedef __attribute__((ext_vector_type(4))) unsigned int u32x4;

__device__ __forceinline__ unsigned short f2bf(float x){
    unsigned int u = __float_as_uint(x);
    return (unsigned short)((u + 0x7fffu + ((u >> 16) & 1u)) >> 16);
}
__device__ __forceinline__ float bf2f(unsigned short u){
    return __uint_as_float(((unsigned int)u) << 16);
}

// elementwise bf16x8 product, f32 math, packed back to bf16 via v_cvt_pk_bf16_f32
__device__ __forceinline__ bf16x8 bfmul8(bf16x8 m, bf16x8 a){
    u32x4 mu = __builtin_bit_cast(u32x4, m);
    u32x4 au = __builtin_bit_cast(u32x4, a);
    u32x4 pu;
    #pragma unroll
    for (int j = 0; j < 4; j++){
        float m0 = __uint_as_float(mu[j] << 16);
        float m1 = __uint_as_float(mu[j] & 0xffff0000u);
        float a0 = __uint_as_float(au[j] << 16);
        float a1 = __uint_as_float(au[j] & 0xffff0000u);
        float p0 = m0 * a0, p1 = m1 * a1;
        unsigned int pk;
        asm("v_cvt_pk_bf16_f32 %0, %1, %2" : "=v"(pk) : "v"(p0), "v"(p1));
        pu[j] = pk;
    }
    return __builtin_bit_cast(bf16x8, pu);
}

// ---------------------------------------------------------------- prep: g_i cast to bf16
__global__ void k_cast_g(const float* __restrict__ g, unsigned short* __restrict__ out, int n8){
    int c = blockIdx.x * blockDim.x + threadIdx.x;
    if (c >= n8) return;
    const float4* p = reinterpret_cast<const float4*>(g + (size_t)c * 8);
    float4 x0 = p[0], x1 = p[1];
    bf16x8 v;
    v[0]=(short)f2bf(x0.x); v[1]=(short)f2bf(x0.y); v[2]=(short)f2bf(x0.z); v[3]=(short)f2bf(x0.w);
    v[4]=(short)f2bf(x1.x); v[5]=(short)f2bf(x1.y); v[6]=(short)f2bf(x1.z); v[7]=(short)f2bf(x1.w);
    reinterpret_cast<bf16x8*>(out)[c] = v;
}

// ---------------------------------------------------------------- prep: W^T cast to bf16, zero-padded
__global__ void k_castT(const float* __restrict__ W, unsigned short* __restrict__ out,
                        int Ntot, int K, int nvalid, int kvalid, int ld, int koff){
    int idx = blockIdx.x * blockDim.x + threadIdx.x;
    int total = Ntot * K;
    if (idx >= total) return;
    int n = idx / K, k = idx - n * K;
    float v = (n < nvalid && k < kvalid) ? W[(size_t)(k + koff) * ld + n] : 0.f;
    out[idx] = f2bf(v);
}

// ---------------------------------------------------------------- prep: phi table (210 combos) @ W1_phi + b1
__global__ void k_phiw(const float* __restrict__ de, const float* __restrict__ ge,
                       const float* __restrict__ se, const float* __restrict__ W1,
                       const float* __restrict__ b1, float* __restrict__ PhiW){
    int c = blockIdx.x;      // 0..209
    int h = threadIdx.x;
    if (h >= HIDP) return;
    int si = c % 3, gi2 = (c / 3) % 7, di = c / 21;
    float acc = 0.f;
    if (h < HID){
        acc = b1[h];
        #pragma unroll
        for (int d = 0; d < 20; d++) acc += de[di*20 + d] * W1[(size_t)(1536 + d) * HID + h];
        #pragma unroll
        for (int d = 0; d < 20; d++) acc += ge[gi2*20 + d] * W1[(size_t)(1556 + d) * HID + h];
        #pragma unroll
        for (int d = 0; d < 20; d++) acc += se[si*20 + d] * W1[(size_t)(1576 + d) * HID + h];
    }
    PhiW[c * HIDP + h] = acc;
}

// ---------------------------------------------------------------- phase 1: Am/Aa projections, barrier-free, no LDS
__global__ __launch_bounds__(256) void k_proj(const unsigned short* __restrict__ g_bf,
                                              const unsigned short* __restrict__ WT,
                                              unsigned short* __restrict__ out){
    const unsigned short* Wh = WT + (size_t)blockIdx.y * 160 * GDIM;
    unsigned short* outh = out + (size_t)blockIdx.y * NROWS * HIDP;
    int tid = threadIdx.x, lane = tid & 63, w = tid >> 6;
    int l15 = lane & 15, lh = lane >> 4;
    int row0 = blockIdx.x * 64;

    int rA = row0 + 16*w + l15; if (rA > NROWS - 1) rA = NROWS - 1;
    const unsigned short* gp = g_bf + (size_t)rA * GDIM + lh * 8;
    const unsigned short* bp = Wh + (size_t)l15 * GDIM + lh * 8;

    f32x4 acc[10];
    #pragma unroll
    for (int t = 0; t < 10; t++) acc[t] = (f32x4){0.f, 0.f, 0.f, 0.f};

    #pragma unroll 4
    for (int ks = 0; ks < 16; ks++){
        bf16x8 a = *reinterpret_cast<const bf16x8*>(gp + ks * 32);
        #pragma unroll
        for (int t = 0; t < 10; t++){
            bf16x8 b = *reinterpret_cast<const bf16x8*>(bp + t * 16 * GDIM + ks * 32);
            acc[t] = __builtin_amdgcn_mfma_f32_16x16x32_bf16(a, b, acc[t], 0, 0, 0);
        }
    }
    #pragma unroll
    for (int t = 0; t < 10; t++){
        #pragma unroll
        for (int i = 0; i < 4; i++){
            int r = row0 + 16*w + 4*lh + i;
            if (r < NROWS) outh[(size_t)r * HIDP + 16*t + l15] = f2bf(acc[t][i]);
        }
    }
}

// ---------------------------------------------------------------- fused pair scorer: barrier-free GEMM1 + epilogue + GEMM2 + scatter
__global__ __launch_bounds__(256) void k_fused(
    const unsigned short* __restrict__ g_bf, const float* __restrict__ ms,
    const unsigned short* __restrict__ W1cT, const unsigned short* __restrict__ W2T,
    const float* __restrict__ PhiW, const unsigned short* __restrict__ Am, const unsigned short* __restrict__ Aa,
    const float* __restrict__ W3, const float* __restrict__ b2, const float* __restrict__ b3,
    const int* __restrict__ mention_ids, const int* __restrict__ antecedent_ids,
    const int* __restrict__ dist_idx, const int* __restrict__ genre_idx, const int* __restrict__ spk_idx,
    const int* __restrict__ seg_ids, const int* __restrict__ pos_in_seg,
    float* __restrict__ dense, int P)
{
    __shared__ short H1_lds[64 * 168];     // 21504 B, per-wave 16-row slabs
    __shared__ int mids[64], aids[64], combos[64];

    int tid = threadIdx.x, lane = tid & 63, w = tid >> 6;
    int l15 = lane & 15, lh = lane >> 4;
    int p0 = blockIdx.x * 64;

    if (tid < 64){
        int p = p0 + tid; int pc = (p < P) ? p : P - 1;
        mids[tid]   = mention_ids[pc];
        aids[tid]   = antecedent_ids[pc];
        combos[tid] = (dist_idx[pc] * 7 + genre_idx[pc]) * 3 + spk_idx[pc];
    }
    __syncthreads();

    // ---- GEMM1: product term, fragments direct from global, zero barriers
    int rA = 16*w + l15;
    const unsigned short* gm = g_bf + (size_t)mids[rA] * GDIM + lh * 8;
    const unsigned short* ga = g_bf + (size_t)aids[rA] * GDIM + lh * 8;
    const unsigned short* bp = W1cT + (size_t)l15 * GDIM + lh * 8;

    f32x4 acc1[10];
    #pragma unroll
    for (int t = 0; t < 10; t++) acc1[t] = (f32x4){0.f, 0.f, 0.f, 0.f};

    #pragma unroll 4
    for (int ks = 0; ks < 16; ks++){
        bf16x8 mv = *reinterpret_cast<const bf16x8*>(gm + ks * 32);
        bf16x8 av = *reinterpret_cast<const bf16x8*>(ga + ks * 32);
        bf16x8 pv = bfmul8(mv, av);
        #pragma unroll
        for (int t = 0; t < 10; t++){
            bf16x8 bv = *reinterpret_cast<const bf16x8*>(bp + t * 16 * GDIM + ks * 32);
            acc1[t] = __builtin_amdgcn_mfma_f32_16x16x32_bf16(pv, bv, acc1[t], 0, 0, 0);
        }
    }

    // ---- epilogue 1: + Am + Aa + PhiW, relu, -> H1 LDS (bf16), D-layout gathers
    #pragma unroll
    for (int i = 0; i < 4; i++){
        int r = 16*w + 4*lh + i;
        int mid = mids[r], aid = aids[r], cmb = combos[r];
        const unsigned short* amp = Am + (size_t)mid * HIDP + l15;
        const unsigned short* aap = Aa + (size_t)aid * HIDP + l15;
        const float*          php = PhiW + cmb * HIDP + l15;
        #pragma unroll
        for (int t = 0; t < 10; t++){
            float v = acc1[t][i] + bf2f(amp[16*t]) + bf2f(aap[16*t]) + php[16*t];
            v = fmaxf(v, 0.f);
            H1_lds[r * 168 + 16*t + l15] = (short)f2bf(v);
        }
    }
    __syncthreads();

    // ---- GEMM2: H1 (LDS) @ W2 (global frags), no staging barriers
    f32x4 acc2[10];
    #pragma unroll
    for (int t = 0; t < 10; t++) acc2[t] = (f32x4){0.f, 0.f, 0.f, 0.f};

    const unsigned short* b2p = W2T + (size_t)l15 * HIDP + lh * 8;
    #pragma unroll
    for (int k2 = 0; k2 < 5; k2++){
        bf16x8 a = *reinterpret_cast<const bf16x8*>(&H1_lds[(16*w + l15) * 168 + k2 * 32 + lh * 8]);
        #pragma unroll
        for (int t = 0; t < 10; t++){
            bf16x8 b = *reinterpret_cast<const bf16x8*>(b2p + t * 16 * HIDP + k2 * 32);
            acc2[t] = __builtin_amdgcn_mfma_f32_16x16x32_bf16(a, b, acc2[t], 0, 0, 0);
        }
    }

    // ---- epilogue 2: relu(+b2), dot W3, + mention scores, scatter into dense
    float w3v[10], b2v[10];
    #pragma unroll
    for (int t = 0; t < 10; t++){
        int h = 16*t + l15;
        w3v[t] = (h < HID) ? W3[h] : 0.f;
        b2v[t] = (h < HID) ? b2[h] : 0.f;
    }
    float b3v = b3[0];
    #pragma unroll
    for (int i = 0; i < 4; i++){
        float s = 0.f;
        #pragma unroll
        for (int t = 0; t < 10; t++) s += fmaxf(acc2[t][i] + b2v[t], 0.f) * w3v[t];
        s += __shfl_xor(s, 1, 16);
        s += __shfl_xor(s, 2, 16);
        s += __shfl_xor(s, 4, 16);
        s += __shfl_xor(s, 8, 16);
        int r = 16*w + 4*lh + i;
        int p = p0 + r;
        if (p < P && l15 == 0){
            float val = s + b3v + ms[mids[r]] + ms[aids[r]];
            dense[(size_t)seg_ids[p] * KP1 + pos_in_seg[p]] = val;
        }
    }
}

// ---------------------------------------------------------------- phase 4: segment softmax, epsilon slot, 1000 padding
__global__ void k_softmax(const float* __restrict__ dense, const int* __restrict__ seg_lengths,
                          float* __restrict__ out, int S){
    int wid = threadIdx.x >> 6, lane = threadIdx.x & 63;
    int s = blockIdx.x * 4 + wid;
    if (s >= S) return;
    int len = seg_lengths[s];
    float ninf = -__builtin_inff();
    float val = ninf;
    if (lane < KP1) val = (lane < len) ? dense[(size_t)s * KP1 + lane] : ((lane == len) ? 0.f : ninf);
    float m = val;
    #pragma unroll
    for (int msk = 1; msk < 64; msk <<= 1) m = fmaxf(m, __shfl_xor(m, msk));
    float e = expf(val - m);
    float sum = e;
    #pragma unroll
    for (int msk = 1; msk < 64; msk <<= 1) sum += __shfl_xor(sum, msk);
    if (lane < KP1) out[(size_t)s * KP1 + lane] = (lane > len) ? 1000.f : (e / sum);
}

// ---------------------------------------------------------------- launch
extern "C" void kernel_launch(void* const* d_in, const int* in_sizes, int n_in,
                              void* d_out, int out_size, void* d_ws, size_t ws_size,
                              hipStream_t stream){
    const float* g_i        = (const float*)d_in[0];
    const float* ms         = (const float*)d_in[1];
    const float* dist_emb   = (const float*)d_in[2];
    const float* genre_emb  = (const float*)d_in[3];
    const float* spk_emb    = (const float*)d_in[4];
    const float* W1         = (const float*)d_in[5];
    const float* b1         = (const float*)d_in[6];
    const float* W2         = (const float*)d_in[7];
    const float* b2         = (const float*)d_in[8];
    const float* W3         = (const float*)d_in[9];
    const float* b3         = (const float*)d_in[10];
    const int* mention_ids  = (const int*)d_in[11];
    const int* antecedent_ids = (const int*)d_in[12];
    const int* dist_idx     = (const int*)d_in[13];
    const int* genre_idx    = (const int*)d_in[14];
    const int* spk_idx      = (const int*)d_in[15];
    const int* seg_ids      = (const int*)d_in[16];
    const int* pos_in_seg   = (const int*)d_in[17];
    const int* seg_lengths  = (const int*)d_in[18];
    int P = in_sizes[11];
    int S = in_sizes[18];

    char* ws = (char*)d_ws;
    unsigned short* W1abT = (unsigned short*)(ws + 0);          // 320*512*2   = 327680
    unsigned short* W1cT  = (unsigned short*)(ws + 327680);     // 160*512*2   = 163840
    unsigned short* W2T   = (unsigned short*)(ws + 491520);     // 160*160*2   = 51200
    float* PhiW           = (float*)(ws + 542720);              // 210*160*4   = 134400 -> 677120
    unsigned short* g_bf  = (unsigned short*)(ws + 677120);     // 12000*512*2 = 12288000 -> 12965120
    unsigned short* AmAa  = (unsigned short*)(ws + 12965120);   // 2*12000*160*2 = 7680000 -> 20645120
    float* dense          = (float*)(ws + 20645120);            // 10001*31*4

    // weight / table prep
    k_cast_g<<<(NROWS*GDIM/8 + 255)/256, 256, 0, stream>>>(g_i, g_bf, NROWS*GDIM/8);
    k_castT<<<(160*512 + 255)/256, 256, 0, stream>>>(W1, W1abT,            160, 512, HID, 512, HID, 0);
    k_castT<<<(160*512 + 255)/256, 256, 0, stream>>>(W1, W1abT + 160*512,  160, 512, HID, 512, HID, 512);
    k_castT<<<(160*512 + 255)/256, 256, 0, stream>>>(W1, W1cT,             160, 512, HID, 512, HID, 1024);
    k_castT<<<(160*160 + 255)/256, 256, 0, stream>>>(W2, W2T,              160, 160, HID, HID, HID, 0);
    k_phiw<<<210, 192, 0, stream>>>(dist_emb, genre_emb, spk_emb, W1, b1, PhiW);

    // row projections Am / Aa (bf16 out)
    k_proj<<<dim3((NROWS + 63)/64, 2), 256, 0, stream>>>(g_bf, W1abT, AmAa);

    // fused pair scorer
    k_fused<<<(P + 63)/64, 256, 0, stream>>>(g_bf, ms, W1cT, W2T, PhiW,
        AmAa, AmAa + (size_t)NROWS*HIDP, W3, b2, b3,
        mention_ids, antecedent_ids, dist_idx, genre_idx, spk_idx,
        seg_ids, pos_in_seg, dense, P);

    // segment softmax
    k_softmax<<<(S + 3)/4, 256, 0, stream>>>(dense, seg_lengths, (float*)d_out, S);
}

// Round 4
// 140.652 us; speedup vs baseline: 2.4769x; 2.4769x over previous
//
#include <hip/hip_runtime.h>
#include <stdint.h>

#define GDIM   512
#define HID    150
#define HIDP   160    // HID padded to multiple of 16
#define NROWS  12000
#define KP1    31     // KMAX+1
#define BM     128    // pairs (or rows) per block
#define H1S    168    // H1 LDS row stride in elems (336B, 16B-aligned, conflict-light)

typedef __attribute__((ext_vector_type(8))) short bf16x8;
typedef __attribute__((ext_vector_type(4))) float f32x4;
typedef __attribute__((ext_vector_type(4))) unsigned int u32x4;

__device__ __forceinline__ unsigned short f2bf(float x){
    unsigned int u = __float_as_uint(x);
    return (unsigned short)((u + 0x7fffu + ((u >> 16) & 1u)) >> 16);
}
__device__ __forceinline__ float bf2f(unsigned short u){
    return __uint_as_float(((unsigned int)u) << 16);
}
__device__ __forceinline__ unsigned int cvtpk(float a, float b){
    unsigned int r; asm("v_cvt_pk_bf16_f32 %0, %1, %2" : "=v"(r) : "v"(a), "v"(b)); return r;
}
// elementwise bf16x8 product, f32 math, packed back to bf16
__device__ __forceinline__ bf16x8 bfmul8(bf16x8 m, bf16x8 a){
    u32x4 mu = __builtin_bit_cast(u32x4, m);
    u32x4 au = __builtin_bit_cast(u32x4, a);
    u32x4 pu;
    #pragma unroll
    for (int j = 0; j < 4; j++){
        float m0 = __uint_as_float(mu[j] << 16);
        float m1 = __uint_as_float(mu[j] & 0xffff0000u);
        float a0 = __uint_as_float(au[j] << 16);
        float a1 = __uint_as_float(au[j] & 0xffff0000u);
        pu[j] = cvtpk(m0 * a0, m1 * a1);
    }
    return __builtin_bit_cast(bf16x8, pu);
}
// async global->LDS, 16B per lane, linear dest
__device__ __forceinline__ void glds16(const unsigned short* g, void* l){
    __builtin_amdgcn_global_load_lds(
        (const __attribute__((address_space(1))) unsigned int*)g,
        (__attribute__((address_space(3))) unsigned int*)l, 16, 0, 0);
}

// ---------------------------------------------------------------- prep: g_i cast to bf16
__global__ void k_cast_g(const float* __restrict__ g, unsigned short* __restrict__ out, int n8){
    int c = blockIdx.x * blockDim.x + threadIdx.x;
    if (c >= n8) return;
    const float4* p = reinterpret_cast<const float4*>(g + (size_t)c * 8);
    float4 x0 = p[0], x1 = p[1];
    bf16x8 v;
    v[0]=(short)f2bf(x0.x); v[1]=(short)f2bf(x0.y); v[2]=(short)f2bf(x0.z); v[3]=(short)f2bf(x0.w);
    v[4]=(short)f2bf(x1.x); v[5]=(short)f2bf(x1.y); v[6]=(short)f2bf(x1.z); v[7]=(short)f2bf(x1.w);
    reinterpret_cast<bf16x8*>(out)[c] = v;
}

// ---------------------------------------------------------------- prep: W1 slice -> tile-major swizzled LDS images
// out[kt][n][g][e] (8 tiles x 160 rows x 8 granules x 8 elems), granule g holds source granule g^(n&7)
__global__ void k_tiles(const float* __restrict__ W1, unsigned short* __restrict__ out, int koff){
    int idx = blockIdx.x * blockDim.x + threadIdx.x;   // granule id
    if (idx >= 8*160*8) return;
    int g  = idx & 7;
    int n  = (idx >> 3) % 160;
    int kt = idx / 1280;
    int gsrc = g ^ (n & 7);
    int k0 = koff + kt*64 + gsrc*8;
    bf16x8 v;
    #pragma unroll
    for (int e = 0; e < 8; e++){
        float x = (n < HID) ? W1[(size_t)(k0 + e) * HID + n] : 0.f;
        v[e] = (short)f2bf(x);
    }
    reinterpret_cast<bf16x8*>(out)[idx] = v;
}

// ---------------------------------------------------------------- prep: W2^T cast to bf16 [160][160]
__global__ void k_castT(const float* __restrict__ W, unsigned short* __restrict__ out,
                        int Ntot, int K, int nvalid, int kvalid, int ld, int koff){
    int idx = blockIdx.x * blockDim.x + threadIdx.x;
    int total = Ntot * K;
    if (idx >= total) return;
    int n = idx / K, k = idx - n * K;
    float v = (n < nvalid && k < kvalid) ? W[(size_t)(k + koff) * ld + n] : 0.f;
    out[idx] = f2bf(v);
}

// ---------------------------------------------------------------- prep: phi table (210 combos) @ W1_phi + b1, bf16
__global__ void k_phiw(const float* __restrict__ de, const float* __restrict__ ge,
                       const float* __restrict__ se, const float* __restrict__ W1,
                       const float* __restrict__ b1, unsigned short* __restrict__ PhiW){
    int c = blockIdx.x;      // 0..209
    int h = threadIdx.x;
    if (h >= HIDP) return;
    int si = c % 3, gi2 = (c / 3) % 7, di = c / 21;
    float acc = 0.f;
    if (h < HID){
        acc = b1[h];
        #pragma unroll
        for (int d = 0; d < 20; d++) acc += de[di*20 + d] * W1[(size_t)(1536 + d) * HID + h];
        #pragma unroll
        for (int d = 0; d < 20; d++) acc += ge[gi2*20 + d] * W1[(size_t)(1556 + d) * HID + h];
        #pragma unroll
        for (int d = 0; d < 20; d++) acc += se[si*20 + d] * W1[(size_t)(1576 + d) * HID + h];
    }
    PhiW[c * HIDP + h] = f2bf(acc);
}

// ---------------------------------------------------------------- prep: padded W3 / b2 (f32, 160)
__global__ void k_pad(const float* __restrict__ W3, const float* __restrict__ b2,
                      float* __restrict__ w3p, float* __restrict__ b2p){
    int h = threadIdx.x; if (h >= HIDP) return;
    w3p[h] = (h < HID) ? W3[h] : 0.f;
    b2p[h] = (h < HID) ? b2[h] : 0.f;
}

// ================================================================ phase 1: Am/Aa projections
__global__ __launch_bounds__(256, 3) void k_proj(const unsigned short* __restrict__ g_bf,
                                                 const unsigned short* __restrict__ Wtiles,
                                                 unsigned short* __restrict__ out){
    __shared__ char smem[40960];                      // 2 x 20480 B buffers
    const unsigned short* Wt = Wtiles + (size_t)blockIdx.y * 81920;   // elems
    unsigned short* outh = out + (size_t)blockIdx.y * NROWS * HIDP;
    int tid = threadIdx.x, lane = tid & 63, w = tid >> 6;
    int l15 = lane & 15, lh = lane >> 4;
    int swz = (l15 & 7) << 4;
    int row0 = blockIdx.x * BM;

    int r0 = row0 + 32*w + l15;       int r0c = (r0 < NROWS) ? r0 : NROWS - 1;
    int r1 = r0 + 16;                 int r1c = (r1 < NROWS) ? r1 : NROWS - 1;
    const unsigned short* gp0 = g_bf + (size_t)r0c * GDIM + lh * 8;
    const unsigned short* gp1 = g_bf + (size_t)r1c * GDIM + lh * 8;

    f32x4 acc1[10][2];
    #pragma unroll
    for (int t = 0; t < 10; t++){ acc1[t][0] = (f32x4){0,0,0,0}; acc1[t][1] = (f32x4){0,0,0,0}; }

#define STAGEP(kt, dst) do{ \
    _Pragma("unroll") \
    for (int i_ = 0; i_ < 5; i_++){ \
        int c_ = w*5 + i_; \
        glds16(Wt + (size_t)(kt)*10240 + c_*512 + lane*8, (dst) + c_*1024); \
    } \
}while(0)
#define LOADAP(kt, R) do{ \
    R[0] = *reinterpret_cast<const bf16x8*>(gp0 + (kt)*64); \
    R[1] = *reinterpret_cast<const bf16x8*>(gp0 + (kt)*64 + 32); \
    R[2] = *reinterpret_cast<const bf16x8*>(gp1 + (kt)*64); \
    R[3] = *reinterpret_cast<const bf16x8*>(gp1 + (kt)*64 + 32); \
}while(0)
#define PHASEP(A, buf) do{ \
    _Pragma("unroll") \
    for (int kh = 0; kh < 2; kh++){ \
        int off_ = l15*128 + ((kh*64 + lh*16) ^ swz); \
        _Pragma("unroll") \
        for (int t = 0; t < 10; t++){ \
            bf16x8 wf = *reinterpret_cast<const bf16x8*>((buf) + t*2048 + off_); \
            acc1[t][0] = __builtin_amdgcn_mfma_f32_16x16x32_bf16(wf, A[kh],   acc1[t][0], 0,0,0); \
            acc1[t][1] = __builtin_amdgcn_mfma_f32_16x16x32_bf16(wf, A[2+kh], acc1[t][1], 0,0,0); \
        } \
    } \
}while(0)

    bf16x8 A0[4], A1[4];
    STAGEP(0, smem);
    LOADAP(0, A0);
    __syncthreads();
    #pragma unroll
    for (int kt2 = 0; kt2 < 8; kt2 += 2){
        STAGEP(kt2+1, smem + 20480); LOADAP(kt2+1, A1);
        PHASEP(A0, smem);
        __syncthreads();
        if (kt2 + 2 < 8){ STAGEP(kt2+2, smem); LOADAP(kt2+2, A0); }
        PHASEP(A1, smem + 20480);
        __syncthreads();
    }

    // epilogue: pack 4 consecutive h per lane, 8B stores
    #pragma unroll
    for (int rf = 0; rf < 2; rf++){
        int row = row0 + 32*w + 16*rf + l15;
        if (row < NROWS){
            #pragma unroll
            for (int t = 0; t < 10; t++){
                f32x4 a = acc1[t][rf];
                uint2 pk; pk.x = cvtpk(a[0], a[1]); pk.y = cvtpk(a[2], a[3]);
                *reinterpret_cast<uint2*>(outh + (size_t)row * HIDP + 16*t + 4*lh) = pk;
            }
        }
    }
#undef STAGEP
#undef LOADAP
#undef PHASEP
}

// ================================================================ fused pair scorer
__global__ __launch_bounds__(256, 3) void k_fused(
    const unsigned short* __restrict__ g_bf, const float* __restrict__ ms,
    const unsigned short* __restrict__ Wc_tiles, const unsigned short* __restrict__ W2T,
    const unsigned short* __restrict__ PhiW, const unsigned short* __restrict__ Am,
    const unsigned short* __restrict__ Aa,
    const float* __restrict__ w3p, const float* __restrict__ b2p, const float* __restrict__ b3,
    const int* __restrict__ mention_ids, const int* __restrict__ antecedent_ids,
    const int* __restrict__ dist_idx, const int* __restrict__ genre_idx, const int* __restrict__ spk_idx,
    const int* __restrict__ seg_ids, const int* __restrict__ pos_in_seg,
    float* __restrict__ dense, int P)
{
    __shared__ char smem[43008];          // [0,20480) buf0 | [20480,40960) buf1 ; alias H1[128][168] bf16 = 43008
    __shared__ int mids[BM], aids[BM], combos[BM];

    int tid = threadIdx.x, lane = tid & 63, w = tid >> 6;
    int l15 = lane & 15, lh = lane >> 4;
    int swz = (l15 & 7) << 4;
    int p0 = blockIdx.x * BM;

    if (tid < BM){
        int p = p0 + tid; int pc = (p < P) ? p : P - 1;
        mids[tid]   = mention_ids[pc];
        aids[tid]   = antecedent_ids[pc];
        combos[tid] = (dist_idx[pc] * 7 + genre_idx[pc]) * 3 + spk_idx[pc];
    }
    __syncthreads();

    int pr0 = 32*w + l15, pr1 = pr0 + 16;
    const unsigned short* gm0 = g_bf + (size_t)mids[pr0] * GDIM + lh * 8;
    const unsigned short* ga0 = g_bf + (size_t)aids[pr0] * GDIM + lh * 8;
    const unsigned short* gm1 = g_bf + (size_t)mids[pr1] * GDIM + lh * 8;
    const unsigned short* ga1 = g_bf + (size_t)aids[pr1] * GDIM + lh * 8;

    f32x4 acc1[10][2];
    #pragma unroll
    for (int t = 0; t < 10; t++){ acc1[t][0] = (f32x4){0,0,0,0}; acc1[t][1] = (f32x4){0,0,0,0}; }

#define STAGEF(kt, dst) do{ \
    _Pragma("unroll") \
    for (int i_ = 0; i_ < 5; i_++){ \
        int c_ = w*5 + i_; \
        glds16(Wc_tiles + (size_t)(kt)*10240 + c_*512 + lane*8, (dst) + c_*1024); \
    } \
}while(0)
#define LOADAF(kt, R) do{ \
    R[0] = *reinterpret_cast<const bf16x8*>(gm0 + (kt)*64); \
    R[1] = *reinterpret_cast<const bf16x8*>(ga0 + (kt)*64); \
    R[2] = *reinterpret_cast<const bf16x8*>(gm0 + (kt)*64 + 32); \
    R[3] = *reinterpret_cast<const bf16x8*>(ga0 + (kt)*64 + 32); \
    R[4] = *reinterpret_cast<const bf16x8*>(gm1 + (kt)*64); \
    R[5] = *reinterpret_cast<const bf16x8*>(ga1 + (kt)*64); \
    R[6] = *reinterpret_cast<const bf16x8*>(gm1 + (kt)*64 + 32); \
    R[7] = *reinterpret_cast<const bf16x8*>(ga1 + (kt)*64 + 32); \
}while(0)
#define PHASEF(A, buf) do{ \
    _Pragma("unroll") \
    for (int kh = 0; kh < 2; kh++){ \
        bf16x8 pv0 = bfmul8(A[0 + kh*2], A[1 + kh*2]); \
        bf16x8 pv1 = bfmul8(A[4 + kh*2], A[5 + kh*2]); \
        int off_ = l15*128 + ((kh*64 + lh*16) ^ swz); \
        _Pragma("unroll") \
        for (int t = 0; t < 10; t++){ \
            bf16x8 wf = *reinterpret_cast<const bf16x8*>((buf) + t*2048 + off_); \
            acc1[t][0] = __builtin_amdgcn_mfma_f32_16x16x32_bf16(wf, pv0, acc1[t][0], 0,0,0); \
            acc1[t][1] = __builtin_amdgcn_mfma_f32_16x16x32_bf16(wf, pv1, acc1[t][1], 0,0,0); \
        } \
    } \
}while(0)

    bf16x8 A0[8], A1[8];
    STAGEF(0, smem);
    LOADAF(0, A0);
    __syncthreads();
    #pragma unroll
    for (int kt2 = 0; kt2 < 8; kt2 += 2){
        STAGEF(kt2+1, smem + 20480); LOADAF(kt2+1, A1);
        PHASEF(A0, smem);
        __syncthreads();
        if (kt2 + 2 < 8){ STAGEF(kt2+2, smem); LOADAF(kt2+2, A0); }
        PHASEF(A1, smem + 20480);
        __syncthreads();
    }
    // all waves past B reads; smem becomes H1 [128][H1S] bf16 (per-wave private slabs)

    // ---- epilogue 1: + Am + Aa + PhiW, relu, bf16-pack -> H1 (8B vector loads/stores)
    #pragma unroll
    for (int rf = 0; rf < 2; rf++){
        int pr = 32*w + 16*rf + l15;
        const unsigned short* amp = Am   + (size_t)mids[pr] * HIDP;
        const unsigned short* aap = Aa   + (size_t)aids[pr] * HIDP;
        const unsigned short* php = PhiW + (size_t)combos[pr] * HIDP;
        char* h1row = smem + pr * (H1S*2);
        #pragma unroll
        for (int t = 0; t < 10; t++){
            int h0 = 16*t + 4*lh;
            ushort4 am4 = *reinterpret_cast<const ushort4*>(amp + h0);
            ushort4 aa4 = *reinterpret_cast<const ushort4*>(aap + h0);
            ushort4 ph4 = *reinterpret_cast<const ushort4*>(php + h0);
            f32x4 a = acc1[t][rf];
            float v0 = fmaxf(a[0] + bf2f(am4.x) + bf2f(aa4.x) + bf2f(ph4.x), 0.f);
            float v1 = fmaxf(a[1] + bf2f(am4.y) + bf2f(aa4.y) + bf2f(ph4.y), 0.f);
            float v2 = fmaxf(a[2] + bf2f(am4.z) + bf2f(aa4.z) + bf2f(ph4.z), 0.f);
            float v3 = fmaxf(a[3] + bf2f(am4.w) + bf2f(aa4.w) + bf2f(ph4.w), 0.f);
            uint2 pk; pk.x = cvtpk(v0, v1); pk.y = cvtpk(v2, v3);
            *reinterpret_cast<uint2*>(h1row + h0*2) = pk;
        }
    }

    // ---- GEMM2: H2 = H1 @ W2 (H1 frags from own-wave LDS slab, W2 frags from global)
    f32x4 acc2[10][2];
    #pragma unroll
    for (int t = 0; t < 10; t++){ acc2[t][0] = (f32x4){0,0,0,0}; acc2[t][1] = (f32x4){0,0,0,0}; }
    const unsigned short* w2pb = W2T + (size_t)l15 * HIDP + lh * 8;
    #pragma unroll
    for (int k2 = 0; k2 < 5; k2++){
        bf16x8 h0f = *reinterpret_cast<const bf16x8*>(smem + (32*w + l15)      * (H1S*2) + k2*64 + lh*16);
        bf16x8 h1f = *reinterpret_cast<const bf16x8*>(smem + (32*w + 16 + l15) * (H1S*2) + k2*64 + lh*16);
        #pragma unroll
        for (int t = 0; t < 10; t++){
            bf16x8 wf = *reinterpret_cast<const bf16x8*>(w2pb + t * 16 * HIDP + k2 * 32);
            acc2[t][0] = __builtin_amdgcn_mfma_f32_16x16x32_bf16(wf, h0f, acc2[t][0], 0,0,0);
            acc2[t][1] = __builtin_amdgcn_mfma_f32_16x16x32_bf16(wf, h1f, acc2[t][1], 0,0,0);
        }
    }

    // ---- epilogue 2: relu(+b2), dot W3, + mention scores, scatter
    float b3v = b3[0];
    #pragma unroll
    for (int rf = 0; rf < 2; rf++){
        float s = 0.f;
        #pragma unroll
        for (int t = 0; t < 10; t++){
            f32x4 w3v = *reinterpret_cast<const f32x4*>(w3p + 16*t + 4*lh);
            f32x4 b2v = *reinterpret_cast<const f32x4*>(b2p + 16*t + 4*lh);
            f32x4 a = acc2[t][rf];
            s += fmaxf(a[0] + b2v[0], 0.f) * w3v[0];
            s += fmaxf(a[1] + b2v[1], 0.f) * w3v[1];
            s += fmaxf(a[2] + b2v[2], 0.f) * w3v[2];
            s += fmaxf(a[3] + b2v[3], 0.f) * w3v[3];
        }
        s += __shfl_xor(s, 16);
        s += __shfl_xor(s, 32);
        int pr = 32*w + 16*rf + l15;
        int p = p0 + pr;
        if (p < P && lh == 0){
            float val = s + b3v + ms[mids[pr]] + ms[aids[pr]];
            dense[(size_t)seg_ids[p] * KP1 + pos_in_seg[p]] = val;
        }
    }
#undef STAGEF
#undef LOADAF
#undef PHASEF
}

// ---------------------------------------------------------------- phase 4: segment softmax
__global__ void k_softmax(const float* __restrict__ dense, const int* __restrict__ seg_lengths,
                          float* __restrict__ out, int S){
    int wid = threadIdx.x >> 6, lane = threadIdx.x & 63;
    int s = blockIdx.x * 4 + wid;
    if (s >= S) return;
    int len = seg_lengths[s];
    float ninf = -__builtin_inff();
    float val = ninf;
    if (lane < KP1) val = (lane < len) ? dense[(size_t)s * KP1 + lane] : ((lane == len) ? 0.f : ninf);
    float m = val;
    #pragma unroll
    for (int msk = 1; msk < 64; msk <<= 1) m = fmaxf(m, __shfl_xor(m, msk));
    float e = expf(val - m);
    float sum = e;
    #pragma unroll
    for (int msk = 1; msk < 64; msk <<= 1) sum += __shfl_xor(sum, msk);
    if (lane < KP1) out[(size_t)s * KP1 + lane] = (lane > len) ? 1000.f : (e / sum);
}

// ---------------------------------------------------------------- launch
extern "C" void kernel_launch(void* const* d_in, const int* in_sizes, int n_in,
                              void* d_out, int out_size, void* d_ws, size_t ws_size,
                              hipStream_t stream){
    const float* g_i        = (const float*)d_in[0];
    const float* ms         = (const float*)d_in[1];
    const float* dist_emb   = (const float*)d_in[2];
    const float* genre_emb  = (const float*)d_in[3];
    const float* spk_emb    = (const float*)d_in[4];
    const float* W1         = (const float*)d_in[5];
    const float* b1         = (const float*)d_in[6];
    const float* W2         = (const float*)d_in[7];
    const float* b2         = (const float*)d_in[8];
    const float* W3         = (const float*)d_in[9];
    const float* b3         = (const float*)d_in[10];
    const int* mention_ids  = (const int*)d_in[11];
    const int* antecedent_ids = (const int*)d_in[12];
    const int* dist_idx     = (const int*)d_in[13];
    const int* genre_idx    = (const int*)d_in[14];
    const int* spk_idx      = (const int*)d_in[15];
    const int* seg_ids      = (const int*)d_in[16];
    const int* pos_in_seg   = (const int*)d_in[17];
    const int* seg_lengths  = (const int*)d_in[18];
    int P = in_sizes[11];
    int S = in_sizes[18];

    char* ws = (char*)d_ws;
    unsigned short* W1ab_tiles = (unsigned short*)(ws + 0);        // 2 x 163840
    unsigned short* W1c_tiles  = (unsigned short*)(ws + 327680);   // 163840
    unsigned short* W2T        = (unsigned short*)(ws + 491520);   // 51200
    unsigned short* PhiW       = (unsigned short*)(ws + 542720);   // 210*160*2 = 67200
    float* w3pad               = (float*)(ws + 609920);            // 640
    float* b2pad               = (float*)(ws + 610560);            // 640
    unsigned short* g_bf       = (unsigned short*)(ws + 611200);   // 12288000
    unsigned short* AmAa       = (unsigned short*)(ws + 12899200); // 7680000
    float* dense               = (float*)(ws + 20579200);          // 10001*31*4

    // prep
    k_cast_g<<<(NROWS*GDIM/8 + 255)/256, 256, 0, stream>>>(g_i, g_bf, NROWS*GDIM/8);
    k_tiles<<<40, 256, 0, stream>>>(W1, W1ab_tiles,          0);
    k_tiles<<<40, 256, 0, stream>>>(W1, W1ab_tiles + 81920,  512);
    k_tiles<<<40, 256, 0, stream>>>(W1, W1c_tiles,           1024);
    k_castT<<<(160*160 + 255)/256, 256, 0, stream>>>(W2, W2T, 160, 160, HID, HID, HID, 0);
    k_phiw<<<210, 192, 0, stream>>>(dist_emb, genre_emb, spk_emb, W1, b1, PhiW);
    k_pad<<<1, 192, 0, stream>>>(W3, b2, w3pad, b2pad);

    // row projections Am / Aa (bf16)
    k_proj<<<dim3((NROWS + BM - 1)/BM, 2), 256, 0, stream>>>(g_bf, W1ab_tiles, AmAa);

    // fused pair scorer
    k_fused<<<(P + BM - 1)/BM, 256, 0, stream>>>(g_bf, ms, W1c_tiles, W2T, PhiW,
        AmAa, AmAa + (size_t)NROWS*HIDP, w3pad, b2pad, b3,
        mention_ids, antecedent_ids, dist_idx, genre_idx, spk_idx,
        seg_ids, pos_in_seg, dense, P);

    // segment softmax
    k_softmax<<<(S + 3)/4, 256, 0, stream>>>(dense, seg_lengths, (float*)d_out, S);
}